// Round 4
// baseline (302.268 us; speedup 1.0000x reference)
//
#include <hip/hip_runtime.h>

// GCN 2-layer, CSR-gather formulation, padded-bucket CSR build.
//   out[c] = dinv[c] * ( h_s[c] + sum_{e: col=c} h_s[row_e] ) + b,  h_s=(X@W)*dinv
// R13b: channel-sliced L2-resident gather (R13 + compile fix: nontemporal
// stores need native ext_vector_type pointers, not HIP_vector_type).
// The gathers (~95us each, 75% of runtime) are outstanding-miss-limited:
// random 128B rows from a 12.8MB table -> ~30% L2 hit, ~480cy avg latency,
// ~32 MSHR/CU => ~2.2 TB/s cap (measured). Fix: slice channels 4x (slice =
// 3.2MB < 4MB/XCD L2), partition grid so each XCD-pair owns one slice
// (blockIdx%8 -> XCD round-robin). Slice stays L2-resident => ~200cy =>
// ~2.4x miss-limited BW. GEMMs emit sliced layout; gemm2 reads sliced Hb;
// scnt = start*128|cnt packed; eros loads + output stores non-temporal.
// Messages bf16, accum fp32. Requires N < 2^17. Int inputs arrive as int32.

#define BKT_SH 7            // 128 nodes per bucket
#define BKT_CAP 4096        // region per bucket (counts ~2046 +- 45; huge margin)
#define CHUNK 6144          // edges per k_bin block
#define BM 128
#define BK 32

typedef unsigned nuint4 __attribute__((ext_vector_type(4)));
typedef float nfloat4 __attribute__((ext_vector_type(4)));

__device__ __forceinline__ unsigned short f2bf(float f) {
    unsigned u = __builtin_bit_cast(unsigned, f);
    u = (u + 0x7FFF + ((u >> 16) & 1)) >> 16;  // RNE
    return (unsigned short)u;
}
__device__ __forceinline__ float bflo(unsigned u) {  // low bf16 of packed pair
    return __builtin_bit_cast(float, u << 16);
}
__device__ __forceinline__ float bfhi(unsigned u) {  // high bf16 of packed pair
    return __builtin_bit_cast(float, u & 0xFFFF0000u);
}

__global__ __launch_bounds__(256) void k_zero_i(int* __restrict__ p, int n) {
    int i = blockIdx.x * 256 + threadIdx.x;
    if (i < n) p[i] = 0;
}

// (A) block-chunked binning: LDS hist -> LDS scan -> one count-reservation
// atomic per (block,bucket) -> LDS sort by bucket -> run-coalesced writes into
// fixed bucket region [bkt*CAP, (bkt+1)*CAP). cursor zero-init; ends = counts.
__global__ __launch_bounds__(256) void k_bin(const int* __restrict__ row,
                                             const int* __restrict__ col,
                                             int* __restrict__ cursor,
                                             unsigned* __restrict__ bentries,
                                             int E) {
    __shared__ unsigned sorted[CHUNK];        // 24 KB packed entries, bucket order
    __shared__ unsigned short bof[CHUNK];     // 12 KB bucket of sorted[i]
    __shared__ int hist[1024];
    __shared__ int ex0[1024];
    __shared__ int cur[1024];
    __shared__ int gbase[1024];
    __shared__ int tsum[256];
    int b = blockIdx.x, t = threadIdx.x;
    int s0 = b * CHUNK;
    int cnt = E - s0; if (cnt > CHUNK) cnt = CHUNK;

    for (int i = t; i < 1024; i += 256) hist[i] = 0;
    __syncthreads();
    // pass 1: histogram
    for (int i = t; i < cnt; i += 256)
        atomicAdd(&hist[col[s0 + i] >> BKT_SH], 1);
    __syncthreads();
    // scan 1024 bins: thread t owns bins [4t, 4t+4)
    {
        int b0 = hist[4 * t], b1 = hist[4 * t + 1], b2 = hist[4 * t + 2], b3 = hist[4 * t + 3];
        int tot = b0 + b1 + b2 + b3;
        tsum[t] = tot;
        __syncthreads();
#pragma unroll
        for (int d = 1; d < 256; d <<= 1) {
            int x = (t >= d) ? tsum[t - d] : 0;
            __syncthreads();
            tsum[t] += (t >= d) ? x : 0;
            __syncthreads();
        }
        int ex = tsum[t] - tot;  // exclusive across thread groups
        ex0[4 * t] = ex;
        ex0[4 * t + 1] = ex + b0;
        ex0[4 * t + 2] = ex + b0 + b1;
        ex0[4 * t + 3] = ex + b0 + b1 + b2;
        cur[4 * t] = ex0[4 * t];
        cur[4 * t + 1] = ex0[4 * t + 1];
        cur[4 * t + 2] = ex0[4 * t + 2];
        cur[4 * t + 3] = ex0[4 * t + 3];
    }
    __syncthreads();
    // reserve: one atomic per non-empty (block,bucket); region base is fixed
    for (int i = t; i < 1024; i += 256)
        if (hist[i] > 0) gbase[i] = i * BKT_CAP + atomicAdd(&cursor[i], hist[i]);
    // pass 2: LDS sort by bucket (order within bucket irrelevant)
    for (int i = t; i < cnt; i += 256) {
        int c = col[s0 + i], r = row[s0 + i];
        int bkt = c >> BKT_SH;
        int p = atomicAdd(&cur[bkt], 1);
        sorted[p] = ((unsigned)(c & ((1 << BKT_SH) - 1)) << 17) | (unsigned)r;
        bof[p] = (unsigned short)bkt;
    }
    __syncthreads();
    // pass 3: run-coalesced global writes (guard against region overflow)
    for (int i = t; i < cnt; i += 256) {
        int bkt = bof[i];
        int pos = gbase[bkt] + (i - ex0[bkt]);
        if (pos < (bkt + 1) * BKT_CAP) bentries[pos] = sorted[i];
    }
}

// (B) per-bucket counting sort IN PLACE: bentries[b*CAP..] -> row indices
// sorted by destination node; emits scnt[node] = (start<<7)|cnt, dinv[node].
__global__ __launch_bounds__(256) void k_bucket_sort(
    unsigned* __restrict__ bentries, const int* __restrict__ cursor,
    unsigned* __restrict__ scnt, float* __restrict__ dinv, int N) {
    __shared__ int hist[128];
    __shared__ int incl[128];
    __shared__ int cur[128];
    __shared__ int rows[BKT_CAP];  // 16 KB
    int b = blockIdx.x, t = threadIdx.x;
    int base = b * BKT_CAP;
    int cnt = cursor[b];
    if (cnt > BKT_CAP) cnt = BKT_CAP;  // safety clamp (never expected)

    if (t < 128) hist[t] = 0;
    __syncthreads();
    for (int i = t; i < cnt; i += 256)
        atomicAdd(&hist[bentries[base + i] >> 17], 1);
    __syncthreads();
    if (t < 128) incl[t] = hist[t];
    __syncthreads();
#pragma unroll
    for (int d = 1; d < 128; d <<= 1) {
        int x = (t < 128 && t >= d) ? incl[t - d] : 0;
        __syncthreads();
        if (t < 128 && t >= d) incl[t] += x;
        __syncthreads();
    }
    if (t < 128) {
        int ex = incl[t] - hist[t];  // exclusive within bucket
        int node = (b << BKT_SH) + t;
        if (node < N) {
            int h = hist[t] > 127 ? 127 : hist[t];  // deg ~45 max; 7-bit pack
            scnt[node] = ((unsigned)(base + ex) << 7) | (unsigned)h;
            dinv[node] = rsqrtf((float)hist[t] + 1.0f);  // +1 self loop
        }
        cur[t] = ex;
    }
    __syncthreads();
    for (int i = t; i < cnt; i += 256) {
        unsigned en = bentries[base + i];
        int p = atomicAdd(&cur[en >> 17], 1);
        rows[p] = (int)(en & 0x1FFFF);
    }
    __syncthreads();
    for (int i = t; i < cnt; i += 256) bentries[base + i] = (unsigned)rows[i];
}

// Tiled GEMM + row scale, fp32 input, bf16 SLICED output.
// Output layout: outb[(slice*N + row)*16 + ch_in_slice], slice = ch>>4.
__global__ __launch_bounds__(256) void k_gemm_f32in(
    const float* __restrict__ X, const float* __restrict__ W,
    const float* __restrict__ dinv, unsigned short* __restrict__ outb,
    int N, int K) {
    __shared__ float Xs[BK][BM + 4];
    __shared__ float Ws[BK][64];
    int t = threadIdx.x;
    int bm = blockIdx.x * BM;
    int tm = t >> 4, tn = t & 15;

    float acc[8][4];
#pragma unroll
    for (int i = 0; i < 8; ++i)
#pragma unroll
        for (int j = 0; j < 4; ++j) acc[i][j] = 0.f;

    for (int kb = 0; kb < K; kb += BK) {
#pragma unroll
        for (int it = 0; it < 4; ++it) {
            int r = (t >> 3) + 32 * it;       // 0..127
            int grow = bm + r;
            int k4 = t & 7;                   // float4 index within BK
            float4 v = make_float4(0.f, 0.f, 0.f, 0.f);
            if (grow < N) v = *(const float4*)(X + (size_t)grow * K + kb + k4 * 4);
            Xs[k4 * 4 + 0][r] = v.x;
            Xs[k4 * 4 + 1][r] = v.y;
            Xs[k4 * 4 + 2][r] = v.z;
            Xs[k4 * 4 + 3][r] = v.w;
        }
#pragma unroll
        for (int it = 0; it < 2; ++it) {
            int idx = t + 256 * it;           // 0..511 float4s
            ((float4*)Ws)[idx] = ((const float4*)(W + (size_t)kb * 64))[idx];
        }
        __syncthreads();
#pragma unroll
        for (int k = 0; k < BK; ++k) {
            float4 xa = *(const float4*)&Xs[k][tm * 8];
            float4 xb = *(const float4*)&Xs[k][tm * 8 + 4];
            float4 w = *(const float4*)&Ws[k][tn * 4];
            float xs[8] = {xa.x, xa.y, xa.z, xa.w, xb.x, xb.y, xb.z, xb.w};
#pragma unroll
            for (int i = 0; i < 8; ++i) {
                acc[i][0] = fmaf(xs[i], w.x, acc[i][0]);
                acc[i][1] = fmaf(xs[i], w.y, acc[i][1]);
                acc[i][2] = fmaf(xs[i], w.z, acc[i][2]);
                acc[i][3] = fmaf(xs[i], w.w, acc[i][3]);
            }
        }
        __syncthreads();
    }
    int s = tn >> 2;
#pragma unroll
    for (int i = 0; i < 8; ++i) {
        int grow = bm + tm * 8 + i;
        if (grow < N) {
            float sc = dinv[grow];
            ushort4 v;
            v.x = f2bf(acc[i][0] * sc);
            v.y = f2bf(acc[i][1] * sc);
            v.z = f2bf(acc[i][2] * sc);
            v.w = f2bf(acc[i][3] * sc);
            *(ushort4*)(outb + ((size_t)s * N + grow) * 16 + (tn & 3) * 4) = v;
        }
    }
}

// Tiled GEMM + row scale, bf16 SLICED input, bf16 SLICED output.
__global__ __launch_bounds__(256) void k_gemm_bf16in(
    const unsigned short* __restrict__ Xb, const float* __restrict__ W,
    const float* __restrict__ dinv, unsigned short* __restrict__ outb,
    int N, int K) {
    __shared__ float Xs[BK][BM + 4];
    __shared__ float Ws[BK][64];
    int t = threadIdx.x;
    int bm = blockIdx.x * BM;
    int tm = t >> 4, tn = t & 15;

    float acc[8][4];
#pragma unroll
    for (int i = 0; i < 8; ++i)
#pragma unroll
        for (int j = 0; j < 4; ++j) acc[i][j] = 0.f;

    const uint4* Xq = (const uint4*)Xb;
    for (int kb = 0; kb < K; kb += BK) {
        // 128 rows x 32 k bf16 = 512 uint4 (8 bf16 each); 2 per thread
        // sliced source: global 16B chunk qq -> slice qq>>1, half qq&1
#pragma unroll
        for (int it = 0; it < 2; ++it) {
            int idx = t * 2 + it;             // 0..511
            int r = idx >> 2;                 // 0..127
            int q = idx & 3;
            int qq = (kb >> 3) + q;           // global 16B chunk index 0..3
            int grow = bm + r;
            uint4 v = make_uint4(0u, 0u, 0u, 0u);
            if (grow < N) v = Xq[((size_t)(qq >> 1) * N + grow) * 2 + (qq & 1)];
            int k0 = q * 8;
            Xs[k0 + 0][r] = bflo(v.x); Xs[k0 + 1][r] = bfhi(v.x);
            Xs[k0 + 2][r] = bflo(v.y); Xs[k0 + 3][r] = bfhi(v.y);
            Xs[k0 + 4][r] = bflo(v.z); Xs[k0 + 5][r] = bfhi(v.z);
            Xs[k0 + 6][r] = bflo(v.w); Xs[k0 + 7][r] = bfhi(v.w);
        }
#pragma unroll
        for (int it = 0; it < 2; ++it) {
            int idx = t + 256 * it;           // 0..511 float4s
            ((float4*)Ws)[idx] = ((const float4*)(W + (size_t)kb * 64))[idx];
        }
        __syncthreads();
#pragma unroll
        for (int k = 0; k < BK; ++k) {
            float4 xa = *(const float4*)&Xs[k][tm * 8];
            float4 xb = *(const float4*)&Xs[k][tm * 8 + 4];
            float4 w = *(const float4*)&Ws[k][tn * 4];
            float xs[8] = {xa.x, xa.y, xa.z, xa.w, xb.x, xb.y, xb.z, xb.w};
#pragma unroll
            for (int i = 0; i < 8; ++i) {
                acc[i][0] = fmaf(xs[i], w.x, acc[i][0]);
                acc[i][1] = fmaf(xs[i], w.y, acc[i][1]);
                acc[i][2] = fmaf(xs[i], w.z, acc[i][2]);
                acc[i][3] = fmaf(xs[i], w.w, acc[i][3]);
            }
        }
        __syncthreads();
    }
    int s = tn >> 2;
#pragma unroll
    for (int i = 0; i < 8; ++i) {
        int grow = bm + tm * 8 + i;
        if (grow < N) {
            float sc = dinv[grow];
            ushort4 v;
            v.x = f2bf(acc[i][0] * sc);
            v.y = f2bf(acc[i][1] * sc);
            v.z = f2bf(acc[i][2] * sc);
            v.w = f2bf(acc[i][3] * sc);
            *(ushort4*)(outb + ((size_t)s * N + grow) * 16 + (tn & 3) * 4) = v;
        }
    }
}

// Channel-sliced gather. Grid: ((nchunks+1)/2)*8 blocks; blockIdx%8 selects
// the XCD (round-robin dispatch), pairs of XCDs own one 16-channel slice
// (3.2MB, L2-resident). 2 lanes/node x 1 uint4 (16B = 8ch). fp32 accum.
// chunk = (b>>3)*2 + (b&1) covers 0..nchunks-1 exactly once per slice.
// mode 1: relu + bf16 sliced out (dstq). mode 0: fp32 final out (dstf).
__global__ __launch_bounds__(256) void k_gather(
    const uint4* __restrict__ srcq, const int* __restrict__ eros,
    const unsigned* __restrict__ scnt, const float* __restrict__ bias,
    float* __restrict__ dstf, uint4* __restrict__ dstq,
    int N, int nchunks, int mode) {
    int b = blockIdx.x, t = threadIdx.x;
    int s = (b & 7) >> 1;                 // slice 0..3
    int chunk = (b >> 3) * 2 + (b & 1);   // node chunk
    if (chunk >= nchunks) return;
    int node = chunk * 128 + (t >> 1);
    if (node >= N) return;
    int l = t & 1;                        // half-slice lane (8 ch)

    const uint4* su4 = srcq + (size_t)s * N * 2;  // slice base (2 uint4/node)

    uint4 sv = su4[(size_t)node * 2 + l];  // self loop
    float a0 = bflo(sv.x), a1 = bfhi(sv.x);
    float a2 = bflo(sv.y), a3 = bfhi(sv.y);
    float a4 = bflo(sv.z), a5 = bfhi(sv.z);
    float a6 = bflo(sv.w), a7 = bfhi(sv.w);

    unsigned sc_pack = scnt[node];
    int e = (int)(sc_pack >> 7);
    int cnt = (int)(sc_pack & 127u);
    float sc = rsqrtf((float)cnt + 1.0f);
    int eend = e + cnt;
    for (; e + 8 <= eend; e += 8) {
        uint4 v[8];
#pragma unroll
        for (int j = 0; j < 8; ++j) {
            int r = __builtin_nontemporal_load(&eros[e + j]);
            v[j] = su4[(size_t)r * 2 + l];
        }
#pragma unroll
        for (int j = 0; j < 8; ++j) {
            a0 += bflo(v[j].x); a1 += bfhi(v[j].x);
            a2 += bflo(v[j].y); a3 += bfhi(v[j].y);
            a4 += bflo(v[j].z); a5 += bfhi(v[j].z);
            a6 += bflo(v[j].w); a7 += bfhi(v[j].w);
        }
    }
    for (; e + 4 <= eend; e += 4) {
        uint4 v[4];
#pragma unroll
        for (int j = 0; j < 4; ++j) {
            int r = __builtin_nontemporal_load(&eros[e + j]);
            v[j] = su4[(size_t)r * 2 + l];
        }
#pragma unroll
        for (int j = 0; j < 4; ++j) {
            a0 += bflo(v[j].x); a1 += bfhi(v[j].x);
            a2 += bflo(v[j].y); a3 += bfhi(v[j].y);
            a4 += bflo(v[j].z); a5 += bfhi(v[j].z);
            a6 += bflo(v[j].w); a7 += bfhi(v[j].w);
        }
    }
    for (; e < eend; ++e) {
        int r = __builtin_nontemporal_load(&eros[e]);
        uint4 v = su4[(size_t)r * 2 + l];
        a0 += bflo(v.x); a1 += bfhi(v.x);
        a2 += bflo(v.y); a3 += bfhi(v.y);
        a4 += bflo(v.z); a5 += bfhi(v.z);
        a6 += bflo(v.w); a7 += bfhi(v.w);
    }
    // bias channels [s*16 + l*8, +8)
    const float4* bp = (const float4*)bias;
    float4 b0 = bp[s * 4 + l * 2], b1 = bp[s * 4 + l * 2 + 1];
    a0 = a0 * sc + b0.x; a1 = a1 * sc + b0.y;
    a2 = a2 * sc + b0.z; a3 = a3 * sc + b0.w;
    a4 = a4 * sc + b1.x; a5 = a5 * sc + b1.y;
    a6 = a6 * sc + b1.z; a7 = a7 * sc + b1.w;
    if (mode) {  // relu + bf16 pack -> sliced dst
        a0 = fmaxf(a0, 0.f); a1 = fmaxf(a1, 0.f);
        a2 = fmaxf(a2, 0.f); a3 = fmaxf(a3, 0.f);
        a4 = fmaxf(a4, 0.f); a5 = fmaxf(a5, 0.f);
        a6 = fmaxf(a6, 0.f); a7 = fmaxf(a7, 0.f);
        nuint4 o;
        o.x = (unsigned)f2bf(a0) | ((unsigned)f2bf(a1) << 16);
        o.y = (unsigned)f2bf(a2) | ((unsigned)f2bf(a3) << 16);
        o.z = (unsigned)f2bf(a4) | ((unsigned)f2bf(a5) << 16);
        o.w = (unsigned)f2bf(a6) | ((unsigned)f2bf(a7) << 16);
        nuint4* dp = (nuint4*)&dstq[((size_t)s * N + node) * 2 + l];
        __builtin_nontemporal_store(o, dp);
    } else {     // fp32 final out, natural layout [node][64]
        nfloat4* d = (nfloat4*)(dstf + (size_t)node * 64 + s * 16 + l * 8);
        nfloat4 o0 = {a0, a1, a2, a3};
        nfloat4 o1 = {a4, a5, a6, a7};
        __builtin_nontemporal_store(o0, d);
        __builtin_nontemporal_store(o1, d + 1);
    }
}

extern "C" void kernel_launch(void* const* d_in, const int* in_sizes, int n_in,
                              void* d_out, int out_size, void* d_ws, size_t ws_size,
                              hipStream_t stream) {
    const float* x = (const float*)d_in[0];
    const int* ei = (const int*)d_in[1];  // int32 per harness contract, [2, E]
    const float* W1 = (const float*)d_in[2];
    const float* b1 = (const float*)d_in[3];
    const float* W2 = (const float*)d_in[4];
    const float* b2 = (const float*)d_in[5];

    int N = in_sizes[0] / 128;  // 100000
    int E = in_sizes[1] / 2;    // 1600000
    const int* row = ei;
    const int* col = ei + E;
    int nb = (N + (1 << BKT_SH) - 1) >> BKT_SH;  // 782 buckets
    int nchunks = (N + 127) / 128;               // 782 gather chunks

    char* ws = (char*)d_ws;
    int* cursor = (int*)ws;                          // nb ints @ 0
    unsigned* scnt = (unsigned*)(ws + (1 << 16));    // N u32 @ 64 KB
    float* dinv = (float*)(ws + (1 << 19));          // N floats @ 512 KB
    unsigned* bentries = (unsigned*)(ws + (2 << 20));    // nb*CAP u32 @ 2 MB (12.8 MB)
    unsigned short* Ab = (unsigned short*)(ws + (15 << 20));  // N*64 bf16 sliced @ 15 MB
    unsigned short* Hb = (unsigned short*)d_out;     // bf16 h2 sliced scratch in d_out
    float* OUTF = (float*)d_out;                     // final fp32 output

    int gemmblk = (N + BM - 1) / BM;       // 782
    int binblk = (E + CHUNK - 1) / CHUNK;  // 261
    int gblk = ((nchunks + 1) / 2) * 8;    // 3128 (slice-partitioned)

    // --- CSR build (padded buckets; once, shared by both layers) ---
    k_zero_i<<<(nb + 255) / 256, 256, 0, stream>>>(cursor, nb);
    k_bin<<<binblk, 256, 0, stream>>>(row, col, cursor, bentries, E);
    k_bucket_sort<<<nb, 256, 0, stream>>>(bentries, cursor, scnt, dinv, N);

    // Layer 1: Ab = bf16((X@W1)*dinv) sliced; Hb = bf16(relu(gather*dinv+b1)) sliced
    k_gemm_f32in<<<gemmblk, 256, 0, stream>>>(x, W1, dinv, Ab, N, 128);
    k_gather<<<gblk, 256, 0, stream>>>((const uint4*)Ab, (const int*)bentries,
                                       scnt, b1, nullptr, (uint4*)Hb, N, nchunks, 1);

    // Layer 2: Ab = bf16((Hb@W2)*dinv) sliced; d_out = gather*dinv + b2 (fp32)
    k_gemm_bf16in<<<gemmblk, 256, 0, stream>>>(Hb, W2, dinv, Ab, N, 64);
    k_gather<<<gblk, 256, 0, stream>>>((const uint4*)Ab, (const int*)bentries,
                                       scnt, b2, OUTF, nullptr, N, nchunks, 0);
}